// Round 1
// baseline (318.219 us; speedup 1.0000x reference)
//
#include <hip/hip_runtime.h>
#include <hip/hip_bf16.h>

typedef __attribute__((ext_vector_type(8))) short short8;
typedef __attribute__((ext_vector_type(4))) float f32x4;

__device__ inline unsigned short f2bf(float x) {
  unsigned u = __float_as_uint(x);
  unsigned rounding = 0x7FFFu + ((u >> 16) & 1u);
  return (unsigned short)((u + rounding) >> 16);
}
__device__ inline float bf2f(unsigned short u) {
  return __uint_as_float(((unsigned)u) << 16);
}
__device__ inline void gload_lds16(const void* g, void* l) {
  __builtin_amdgcn_global_load_lds(
      (const __attribute__((address_space(1))) unsigned int*)g,
      (__attribute__((address_space(3))) unsigned int*)l, 16, 0, 0);
}

// ---------------------------------------------------------------------------
// Kernel 1: pair decode + rasterize + slicing output
// ---------------------------------------------------------------------------
__global__ void prep_pairs(const float* __restrict__ bboxes,
                           const int* __restrict__ num_obj, int M,
                           int* __restrict__ pairTab,
                           float* __restrict__ slicing) {
  __shared__ int cum[9];
  if (threadIdx.x == 0) {
    int c = 0; cum[0] = 0;
    for (int b = 0; b < 8; b++) { int n = num_obj[b]; c += n*(n-1)/2; cum[b+1] = c; }
  }
  __syncthreads();
  for (int m = threadIdx.x; m < M; m += blockDim.x) {
    int b = 0;
    while (b < 7 && m >= cum[b+1]) b++;
    int p = m - cum[b];
    int n = num_obj[b];
    int i = 0, rem = p;
    while (rem >= (n - 1 - i)) { rem -= (n - 1 - i); i++; }
    int j = i + 1 + rem;
    const float* A = bboxes + (b*24 + i)*4;
    const float* Bb = bboxes + (b*24 + j)*4;
    float ax1=A[0], ay1=A[1], ax2=A[2], ay2=A[3];
    float bx1=Bb[0], by1=Bb[1], bx2=Bb[2], by2=Bb[3];
    float u1 = fminf(ax1,bx1), v1 = fminf(ay1,by1);
    float u2 = fmaxf(ax2,bx2), v2 = fmaxf(ay2,by2);
    float w = u2-u1, h = v2-v1;
    float scale = 63.0f / fmaxf(fmaxf(w,h), 1e-6f);
    float offx = (h >= w) ? __fmul_rn(63.0f - __fmul_rn(w,scale), 0.5f) : 0.0f;
    float offy = (w > h)  ? __fmul_rn(63.0f - __fmul_rn(h,scale), 0.5f) : 0.0f;
    int* t = pairTab + m*8;
    t[0] = (int)rintf(__fadd_rn(__fmul_rn(ax1-u1, scale), offx));
    t[1] = (int)rintf(__fadd_rn(__fmul_rn(ay1-v1, scale), offy));
    t[2] = (int)rintf(__fadd_rn(__fmul_rn(ax2-u1, scale), offx));
    t[3] = (int)rintf(__fadd_rn(__fmul_rn(ay2-v1, scale), offy));
    t[4] = (int)rintf(__fadd_rn(__fmul_rn(bx1-u1, scale), offx));
    t[5] = (int)rintf(__fadd_rn(__fmul_rn(by1-v1, scale), offy));
    t[6] = (int)rintf(__fadd_rn(__fmul_rn(bx2-u1, scale), offx));
    t[7] = (int)rintf(__fadd_rn(__fmul_rn(by2-v1, scale), offy));
    slicing[m*3+0] = (float)b;
    slicing[m*3+1] = (float)i;
    slicing[m*3+2] = (float)j;
  }
}

// ---------------------------------------------------------------------------
// Kernel 2: conv1 range-sum table T[c][ry26][rx26][64] + conv2 weights reorder
// W2A layout: bf16, index ((kk*2+mt)*64 + lane)*8 + j
//   k = kk*32 + (lane>>4)*8 + j ; k = half*800 + (ky*5+kx)*32 + icl ; ic = half*32+icl
// ---------------------------------------------------------------------------
__global__ void prep_tables(const float* __restrict__ w1, const float* __restrict__ w2,
                            float* __restrict__ T, unsigned short* __restrict__ W2A) {
  int idx = blockIdx.x*256 + threadIdx.x;
  if (idx < 86528) {
    int o = idx & 63;
    int t = idx >> 6;
    int rxi = t % 26; t /= 26;
    int ryi = t % 26;
    int c = t / 26;
    int ky0 = ryi/5, ky1 = ryi%5, kx0 = rxi/5, kx1 = rxi%5;
    float s = 0.f;
    for (int ky = ky0; ky <= ky1; ky++)
      for (int kx = kx0; kx <= kx1; kx++)
        s += w1[((o*2 + c)*5 + ky)*5 + kx];
    T[idx] = s;
  } else if (idx < 86528 + 51200) {
    int i = idx - 86528;
    int j = i & 7, ln = (i>>3) & 63;
    int mtk = i >> 9;
    int mt = mtk & 1, kk = mtk >> 1;
    int oc = mt*16 + (ln & 15);
    int k = kk*32 + ((ln>>4)<<3) + j;
    int halfk = k/800, r = k%800;
    int kyx = r >> 5, icl = r & 31;
    int ic = halfk*32 + icl, ky = kyx/5, kx = kyx%5;
    W2A[i] = f2bf(w2[((oc*64 + ic)*5 + ky)*5 + kx]);
  }
}

// ---------------------------------------------------------------------------
// Kernel 3: transpose+cast lin_w [5408][4800] f32 -> Wt [4800][5408] bf16
// ---------------------------------------------------------------------------
__global__ __launch_bounds__(256) void prep_wt(const float* __restrict__ lw,
                                               unsigned short* __restrict__ Wt) {
  __shared__ unsigned short tile[64][65];
  int k0 = blockIdx.x*64, n0 = blockIdx.y*64;
  for (int i = threadIdx.x; i < 64*64; i += 256) {
    int r = i >> 6, cdx = i & 63;
    int k = k0 + r, n = n0 + cdx;
    float v = (k < 5408) ? lw[(size_t)k*4800 + n] : 0.f;
    tile[r][cdx] = f2bf(v);
  }
  __syncthreads();
  for (int i = threadIdx.x; i < 64*64; i += 256) {
    int r = i >> 6, cdx = i & 63;
    int n = n0 + r, k = k0 + cdx;
    if (k < 5408) Wt[(size_t)n*5408 + k] = tile[cdx][r];
  }
}

// ---------------------------------------------------------------------------
// Kernel 4: per-pair conv pipeline. One block per pair, 256 threads.
// LDS pooled1 [900 pos][32 ch] bf16 per ic-half, XOR-swizzled 16B slots.
// conv2 via mfma_16x16x32_bf16, A=w2 [32 x 1600], B=im2col from LDS.
// ---------------------------------------------------------------------------
__global__ __launch_bounds__(256) void pair_conv(
    const int* __restrict__ pairTab, const float* __restrict__ T,
    const unsigned short* __restrict__ W2A, const float* __restrict__ b1,
    const float* __restrict__ b2, unsigned short* __restrict__ X) {
  __shared__ unsigned short p1[28800];      // 57600 B
  __shared__ unsigned char rIdx[4][64];     // ryA, ryB, rxA, rxB for q=0..59
  int m = blockIdx.x;
  int tid = threadIdx.x, lane = tid & 63, wid = tid >> 6;
  const int* pt = pairTab + m*8;

  if (tid < 240) {
    int q = tid % 60, which = tid / 60;
    int lo, hi;
    if (which == 0)      { lo = pt[1]; hi = pt[3]; }
    else if (which == 1) { lo = pt[5]; hi = pt[7]; }
    else if (which == 2) { lo = pt[0]; hi = pt[2]; }
    else                 { lo = pt[4]; hi = pt[6]; }
    int k0 = lo - q; if (k0 < 0) k0 = 0;
    int k1 = hi - q; if (k1 > 4) k1 = 4;
    rIdx[which][q] = (k0 > k1) ? (unsigned char)25 : (unsigned char)(k0*5 + k1);
  }

  int rowbase[11];
#pragma unroll
  for (int tt = 0; tt < 11; tt++) {
    int pos = (wid*11 + tt)*16 + (lane & 15);
    if (pos > 675) pos = 675;
    rowbase[tt] = (pos/26)*30 + (pos % 26);
  }
  f32x4 acc[11][2];
#pragma unroll
  for (int tt = 0; tt < 11; tt++) {
    acc[tt][0] = (f32x4){0.f,0.f,0.f,0.f};
    acc[tt][1] = (f32x4){0.f,0.f,0.f,0.f};
  }

  int icgl = lane >> 4;
  for (int half = 0; half < 2; half++) {
    __syncthreads();
    // stage1: conv1 (table lookup) + relu + pool -> pooled1 bf16 in LDS
    for (int item = tid; item < 3600; item += 256) {
      int pos = item >> 2;
      int icg = item & 3;
      int ic0 = half*32 + icg*8;
      int py = pos / 30, px = pos % 30;
      float best[8];
#pragma unroll
      for (int j = 0; j < 8; j++) best[j] = -1e30f;
#pragma unroll
      for (int d = 0; d < 4; d++) {
        int y = py*2 + (d>>1), x = px*2 + (d&1);
        int rya = rIdx[0][y], ryb = rIdx[1][y];
        int rxa = rIdx[2][x], rxb = rIdx[3][x];
        const float* Ta = T + (((rya)*26 + rxa)<<6) + ic0;
        const float* Tb = T + (((26 + ryb)*26 + rxb)<<6) + ic0;
        f32x4 a0 = *(const f32x4*)Ta, a1 = *(const f32x4*)(Ta+4);
        f32x4 c0 = *(const f32x4*)Tb, c1 = *(const f32x4*)(Tb+4);
#pragma unroll
        for (int j = 0; j < 4; j++) {
          best[j]   = fmaxf(best[j],   a0[j]+c0[j]);
          best[4+j] = fmaxf(best[4+j], a1[j]+c1[j]);
        }
      }
      short8 v;
#pragma unroll
      for (int j = 0; j < 8; j++)
        v[j] = (short)f2bf(fmaxf(best[j] + b1[ic0+j], 0.f));
      int byte = pos*64 + ((icg ^ ((pos>>1)&3))<<4);
      *(short8*)((char*)p1 + byte) = v;
    }
    __syncthreads();
    // stage2: conv2 partial over this ic half (25 K-steps of 32)
    for (int kl = 0; kl < 25; kl++) {
      int kk = half*25 + kl;
      const unsigned short* wptr = W2A + ((size_t)(kk*2)*64 + lane)*8;
      short8 a0 = *(const short8*)wptr;
      short8 a1 = *(const short8*)(wptr + 512);
      int radd = (kl/5)*30 + (kl%5);
#pragma unroll
      for (int tt = 0; tt < 11; tt++) {
        int row = rowbase[tt] + radd;
        int byte = row*64 + ((icgl ^ ((row>>1)&3))<<4);
        short8 bv = *(const short8*)((const char*)p1 + byte);
        acc[tt][0] = __builtin_amdgcn_mfma_f32_16x16x32_bf16(a0, bv, acc[tt][0], 0, 0, 0);
        acc[tt][1] = __builtin_amdgcn_mfma_f32_16x16x32_bf16(a1, bv, acc[tt][1], 0, 0, 0);
      }
    }
  }
  __syncthreads();
  // stage3: dump conv2 (pre-bias) to LDS bf16 [32][676]
#pragma unroll
  for (int tt = 0; tt < 11; tt++) {
    int pos = (wid*11 + tt)*16 + (lane & 15);
    if (pos <= 675) {
#pragma unroll
      for (int mt = 0; mt < 2; mt++)
#pragma unroll
        for (int r = 0; r < 4; r++) {
          int oc = mt*16 + ((lane>>4)<<2) + r;
          p1[oc*676 + pos] = f2bf(acc[tt][mt][r]);
        }
    }
  }
  __syncthreads();
  // pool2 + bias + relu -> X[m][5408] bf16
  for (int f = tid; f < 5408; f += 256) {
    int oc = f / 169, rem = f % 169;
    int py = rem / 13, px = rem % 13;
    const unsigned short* c2 = p1 + oc*676 + py*52 + px*2;
    float v = fmaxf(fmaxf(bf2f(c2[0]), bf2f(c2[1])), fmaxf(bf2f(c2[26]), bf2f(c2[27])));
    X[(size_t)m*5408 + f] = f2bf(fmaxf(v + b2[oc], 0.f));
  }
}

// ---------------------------------------------------------------------------
// Kernel 5: linear GEMM  out[M][4800] = relu(X[M][5408] * W[5408][4800] + b)
// A = X (row-major, k contiguous), B = Wt [4800][5408] (k contiguous).
// 128x128 tile, BK=32, 4 waves 2x2, global_load_lds w/ pre-swizzled source.
// ---------------------------------------------------------------------------
__global__ __launch_bounds__(256) void gemm_lin(
    const unsigned short* __restrict__ X, const unsigned short* __restrict__ Wt,
    const float* __restrict__ lin_b, float* __restrict__ out, int M) {
  __shared__ unsigned short As[4096], Bs[4096];  // 8KB each
  int tid = threadIdx.x, lane = tid & 63, wid = tid >> 6;
  int m0 = blockIdx.x * 128, n0 = blockIdx.y * 128;
  int wm = wid >> 1, wn = wid & 1;
  f32x4 acc[4][4];
#pragma unroll
  for (int i = 0; i < 4; i++)
#pragma unroll
    for (int j = 0; j < 4; j++) acc[i][j] = (f32x4){0.f,0.f,0.f,0.f};

  int rA[2], kcA[2];
#pragma unroll
  for (int cc = 0; cc < 2; cc++) {
    int chunk = wid + cc*4;
    int r = (chunk<<4) + (lane>>2);
    rA[cc] = r;
    kcA[cc] = (lane&3) ^ ((r>>1)&3);
  }
  int kg = lane >> 4;

  for (int k0 = 0; k0 < 5408; k0 += 32) {
    __syncthreads();
#pragma unroll
    for (int cc = 0; cc < 2; cc++) {
      int chunk = wid + cc*4;
      int r = rA[cc], kc = kcA[cc];
      int gm = m0 + r; if (gm > M-1) gm = M-1;
      int gn = n0 + r; if (gn > 4799) gn = 4799;
      gload_lds16(X  + (size_t)gm*5408 + k0 + kc*8, (char*)As + chunk*1024);
      gload_lds16(Wt + (size_t)gn*5408 + k0 + kc*8, (char*)Bs + chunk*1024);
    }
    __syncthreads();
    short8 af[4], bfr[4];
#pragma unroll
    for (int mf = 0; mf < 4; mf++) {
      int row = wm*64 + mf*16 + (lane&15);
      int byte = row*64 + ((kg ^ ((row>>1)&3))<<4);
      af[mf] = *(const short8*)((const char*)As + byte);
    }
#pragma unroll
    for (int nf = 0; nf < 4; nf++) {
      int row = wn*64 + nf*16 + (lane&15);
      int byte = row*64 + ((kg ^ ((row>>1)&3))<<4);
      bfr[nf] = *(const short8*)((const char*)Bs + byte);
    }
#pragma unroll
    for (int mf = 0; mf < 4; mf++)
#pragma unroll
      for (int nf = 0; nf < 4; nf++)
        acc[mf][nf] = __builtin_amdgcn_mfma_f32_16x16x32_bf16(af[mf], bfr[nf], acc[mf][nf], 0, 0, 0);
  }

#pragma unroll
  for (int mf = 0; mf < 4; mf++) {
#pragma unroll
    for (int nf = 0; nf < 4; nf++) {
      int n = n0 + wn*64 + nf*16 + (lane&15);
#pragma unroll
      for (int r = 0; r < 4; r++) {
        int mm = m0 + wm*64 + mf*16 + ((lane>>4)<<2) + r;
        if (mm < M && n < 4800)
          out[(size_t)mm*4800 + n] = fmaxf(acc[mf][nf][r] + lin_b[n], 0.f);
      }
    }
  }
}

// ---------------------------------------------------------------------------
extern "C" void kernel_launch(void* const* d_in, const int* in_sizes, int n_in,
                              void* d_out, int out_size, void* d_ws, size_t ws_size,
                              hipStream_t stream) {
  const float* bboxes = (const float*)d_in[0];
  const int*   num_obj = (const int*)d_in[1];
  const float* w1 = (const float*)d_in[2];
  const float* b1 = (const float*)d_in[3];
  const float* w2 = (const float*)d_in[4];
  const float* b2 = (const float*)d_in[5];
  const float* lw = (const float*)d_in[6];
  const float* lb = (const float*)d_in[7];
  float* out = (float*)d_out;
  int M = out_size / 4803;

  char* ws = (char*)d_ws;
  size_t off = 0;
  auto alloc = [&](size_t bytes) {
    off = (off + 511) & ~(size_t)511;
    char* p = ws + off;
    off += bytes;
    return p;
  };
  int* pairTab = (int*)alloc((size_t)M*8*4);
  float* T = (float*)alloc((size_t)86528*4);
  unsigned short* W2A = (unsigned short*)alloc((size_t)51200*2);
  unsigned short* Wt = (unsigned short*)alloc((size_t)4800*5408*2);
  unsigned short* X = (unsigned short*)alloc((size_t)M*5408*2);

  prep_pairs<<<1, 256, 0, stream>>>(bboxes, num_obj, M, pairTab, out + (size_t)M*4800);
  prep_tables<<<(137728+255)/256, 256, 0, stream>>>(w1, w2, T, W2A);
  prep_wt<<<dim3(85, 75), 256, 0, stream>>>(lw, Wt);
  pair_conv<<<M, 256, 0, stream>>>(pairTab, T, W2A, b1, b2, X);
  gemm_lin<<<dim3((M+127)/128, 38), 256, 0, stream>>>(X, Wt, lb, out, M);
}

// Round 2
// 278.673 us; speedup vs baseline: 1.1419x; 1.1419x over previous
//
#include <hip/hip_runtime.h>
#include <hip/hip_bf16.h>

typedef __attribute__((ext_vector_type(8))) short short8;
typedef __attribute__((ext_vector_type(4))) float f32x4;

__device__ inline unsigned short f2bf(float x) {
  unsigned u = __float_as_uint(x);
  unsigned rounding = 0x7FFFu + ((u >> 16) & 1u);
  return (unsigned short)((u + rounding) >> 16);
}
__device__ inline float bf2f(unsigned short u) {
  return __uint_as_float(((unsigned)u) << 16);
}
__device__ inline void gload_lds16(const void* g, void* l) {
  __builtin_amdgcn_global_load_lds(
      (const __attribute__((address_space(1))) unsigned int*)g,
      (__attribute__((address_space(3))) unsigned int*)l, 16, 0, 0);
}

#define KPAD 5440   // 5408 padded to 85*64
#define NPAD 4864   // 4800 padded to 38*128

// ---------------------------------------------------------------------------
// Kernel 1: pair decode + rasterize + slicing output
// ---------------------------------------------------------------------------
__global__ void prep_pairs(const float* __restrict__ bboxes,
                           const int* __restrict__ num_obj, int M,
                           int* __restrict__ pairTab,
                           float* __restrict__ slicing) {
  __shared__ int cum[9];
  if (threadIdx.x == 0) {
    int c = 0; cum[0] = 0;
    for (int b = 0; b < 8; b++) { int n = num_obj[b]; c += n*(n-1)/2; cum[b+1] = c; }
  }
  __syncthreads();
  for (int m = threadIdx.x; m < M; m += blockDim.x) {
    int b = 0;
    while (b < 7 && m >= cum[b+1]) b++;
    int p = m - cum[b];
    int n = num_obj[b];
    int i = 0, rem = p;
    while (rem >= (n - 1 - i)) { rem -= (n - 1 - i); i++; }
    int j = i + 1 + rem;
    const float* A = bboxes + (b*24 + i)*4;
    const float* Bb = bboxes + (b*24 + j)*4;
    float ax1=A[0], ay1=A[1], ax2=A[2], ay2=A[3];
    float bx1=Bb[0], by1=Bb[1], bx2=Bb[2], by2=Bb[3];
    float u1 = fminf(ax1,bx1), v1 = fminf(ay1,by1);
    float u2 = fmaxf(ax2,bx2), v2 = fmaxf(ay2,by2);
    float w = u2-u1, h = v2-v1;
    float scale = 63.0f / fmaxf(fmaxf(w,h), 1e-6f);
    float offx = (h >= w) ? __fmul_rn(63.0f - __fmul_rn(w,scale), 0.5f) : 0.0f;
    float offy = (w > h)  ? __fmul_rn(63.0f - __fmul_rn(h,scale), 0.5f) : 0.0f;
    int* t = pairTab + m*8;
    t[0] = (int)rintf(__fadd_rn(__fmul_rn(ax1-u1, scale), offx));
    t[1] = (int)rintf(__fadd_rn(__fmul_rn(ay1-v1, scale), offy));
    t[2] = (int)rintf(__fadd_rn(__fmul_rn(ax2-u1, scale), offx));
    t[3] = (int)rintf(__fadd_rn(__fmul_rn(ay2-v1, scale), offy));
    t[4] = (int)rintf(__fadd_rn(__fmul_rn(bx1-u1, scale), offx));
    t[5] = (int)rintf(__fadd_rn(__fmul_rn(by1-v1, scale), offy));
    t[6] = (int)rintf(__fadd_rn(__fmul_rn(bx2-u1, scale), offx));
    t[7] = (int)rintf(__fadd_rn(__fmul_rn(by2-v1, scale), offy));
    slicing[m*3+0] = (float)b;
    slicing[m*3+1] = (float)i;
    slicing[m*3+2] = (float)j;
  }
}

// ---------------------------------------------------------------------------
// Kernel 2: conv1 range-sum table T[c][ry26][rx26][64] + conv2 weights reorder
// ---------------------------------------------------------------------------
__global__ void prep_tables(const float* __restrict__ w1, const float* __restrict__ w2,
                            float* __restrict__ T, unsigned short* __restrict__ W2A) {
  int idx = blockIdx.x*256 + threadIdx.x;
  if (idx < 86528) {
    int o = idx & 63;
    int t = idx >> 6;
    int rxi = t % 26; t /= 26;
    int ryi = t % 26;
    int c = t / 26;
    int ky0 = ryi/5, ky1 = ryi%5, kx0 = rxi/5, kx1 = rxi%5;
    float s = 0.f;
    for (int ky = ky0; ky <= ky1; ky++)
      for (int kx = kx0; kx <= kx1; kx++)
        s += w1[((o*2 + c)*5 + ky)*5 + kx];
    T[idx] = s;
  } else if (idx < 86528 + 51200) {
    int i = idx - 86528;
    int j = i & 7, ln = (i>>3) & 63;
    int mtk = i >> 9;
    int mt = mtk & 1, kk = mtk >> 1;
    int oc = mt*16 + (ln & 15);
    int k = kk*32 + ((ln>>4)<<3) + j;
    int halfk = k/800, r = k%800;
    int kyx = r >> 5, icl = r & 31;
    int ic = halfk*32 + icl, ky = kyx/5, kx = kyx%5;
    W2A[i] = f2bf(w2[((oc*64 + ic)*5 + ky)*5 + kx]);
  }
}

// ---------------------------------------------------------------------------
// Kernel 3: transpose+cast lin_w [5408][4800] f32 -> Wt [4800][KPAD] bf16
// (k-pad region stores zeros)
// ---------------------------------------------------------------------------
__global__ __launch_bounds__(256) void prep_wt(const float* __restrict__ lw,
                                               unsigned short* __restrict__ Wt) {
  __shared__ unsigned short tile[64][65];
  int k0 = blockIdx.x*64, n0 = blockIdx.y*64;
  for (int i = threadIdx.x; i < 64*64; i += 256) {
    int r = i >> 6, cdx = i & 63;
    int k = k0 + r, n = n0 + cdx;
    float v = (k < 5408) ? lw[(size_t)k*4800 + n] : 0.f;
    tile[r][cdx] = f2bf(v);
  }
  __syncthreads();
  for (int i = threadIdx.x; i < 64*64; i += 256) {
    int r = i >> 6, cdx = i & 63;
    int n = n0 + r, k = k0 + cdx;
    Wt[(size_t)n*KPAD + k] = tile[cdx][r];
  }
}

// ---------------------------------------------------------------------------
// Kernel 4: per-pair conv pipeline. One block per pair, 256 threads.
// ---------------------------------------------------------------------------
__global__ __launch_bounds__(256) void pair_conv(
    const int* __restrict__ pairTab, const float* __restrict__ T,
    const unsigned short* __restrict__ W2A, const float* __restrict__ b1,
    const float* __restrict__ b2, unsigned short* __restrict__ X) {
  __shared__ unsigned short p1[28800];      // 57600 B
  __shared__ unsigned char rIdx[4][64];
  int m = blockIdx.x;
  int tid = threadIdx.x, lane = tid & 63, wid = tid >> 6;
  const int* pt = pairTab + m*8;

  if (tid < 240) {
    int q = tid % 60, which = tid / 60;
    int lo, hi;
    if (which == 0)      { lo = pt[1]; hi = pt[3]; }
    else if (which == 1) { lo = pt[5]; hi = pt[7]; }
    else if (which == 2) { lo = pt[0]; hi = pt[2]; }
    else                 { lo = pt[4]; hi = pt[6]; }
    int k0 = lo - q; if (k0 < 0) k0 = 0;
    int k1 = hi - q; if (k1 > 4) k1 = 4;
    rIdx[which][q] = (k0 > k1) ? (unsigned char)25 : (unsigned char)(k0*5 + k1);
  }

  int rowbase[11];
#pragma unroll
  for (int tt = 0; tt < 11; tt++) {
    int pos = (wid*11 + tt)*16 + (lane & 15);
    if (pos > 675) pos = 675;
    rowbase[tt] = (pos/26)*30 + (pos % 26);
  }
  f32x4 acc[11][2];
#pragma unroll
  for (int tt = 0; tt < 11; tt++) {
    acc[tt][0] = (f32x4){0.f,0.f,0.f,0.f};
    acc[tt][1] = (f32x4){0.f,0.f,0.f,0.f};
  }

  int icgl = lane >> 4;
  for (int half = 0; half < 2; half++) {
    __syncthreads();
    for (int item = tid; item < 3600; item += 256) {
      int pos = item >> 2;
      int icg = item & 3;
      int ic0 = half*32 + icg*8;
      int py = pos / 30, px = pos % 30;
      float best[8];
#pragma unroll
      for (int j = 0; j < 8; j++) best[j] = -1e30f;
#pragma unroll
      for (int d = 0; d < 4; d++) {
        int y = py*2 + (d>>1), x = px*2 + (d&1);
        int rya = rIdx[0][y], ryb = rIdx[1][y];
        int rxa = rIdx[2][x], rxb = rIdx[3][x];
        const float* Ta = T + (((rya)*26 + rxa)<<6) + ic0;
        const float* Tb = T + (((26 + ryb)*26 + rxb)<<6) + ic0;
        f32x4 a0 = *(const f32x4*)Ta, a1 = *(const f32x4*)(Ta+4);
        f32x4 c0 = *(const f32x4*)Tb, c1 = *(const f32x4*)(Tb+4);
#pragma unroll
        for (int j = 0; j < 4; j++) {
          best[j]   = fmaxf(best[j],   a0[j]+c0[j]);
          best[4+j] = fmaxf(best[4+j], a1[j]+c1[j]);
        }
      }
      short8 v;
#pragma unroll
      for (int j = 0; j < 8; j++)
        v[j] = (short)f2bf(fmaxf(best[j] + b1[ic0+j], 0.f));
      int byte = pos*64 + ((icg ^ ((pos>>1)&3))<<4);
      *(short8*)((char*)p1 + byte) = v;
    }
    __syncthreads();
    for (int kl = 0; kl < 25; kl++) {
      int kk = half*25 + kl;
      const unsigned short* wptr = W2A + ((size_t)(kk*2)*64 + lane)*8;
      short8 a0 = *(const short8*)wptr;
      short8 a1 = *(const short8*)(wptr + 512);
      int radd = (kl/5)*30 + (kl%5);
#pragma unroll
      for (int tt = 0; tt < 11; tt++) {
        int row = rowbase[tt] + radd;
        int byte = row*64 + ((icgl ^ ((row>>1)&3))<<4);
        short8 bv = *(const short8*)((const char*)p1 + byte);
        acc[tt][0] = __builtin_amdgcn_mfma_f32_16x16x32_bf16(a0, bv, acc[tt][0], 0, 0, 0);
        acc[tt][1] = __builtin_amdgcn_mfma_f32_16x16x32_bf16(a1, bv, acc[tt][1], 0, 0, 0);
      }
    }
  }
  __syncthreads();
#pragma unroll
  for (int tt = 0; tt < 11; tt++) {
    int pos = (wid*11 + tt)*16 + (lane & 15);
    if (pos <= 675) {
#pragma unroll
      for (int mt = 0; mt < 2; mt++)
#pragma unroll
        for (int r = 0; r < 4; r++) {
          int oc = mt*16 + ((lane>>4)<<2) + r;
          p1[oc*676 + pos] = f2bf(acc[tt][mt][r]);
        }
    }
  }
  __syncthreads();
  // pool2 + bias + relu -> X[m][KPAD] bf16 (zero the k-pad)
  for (int f = tid; f < KPAD; f += 256) {
    unsigned short outv = 0;
    if (f < 5408) {
      int oc = f / 169, rem = f % 169;
      int py = rem / 13, px = rem % 13;
      const unsigned short* c2 = p1 + oc*676 + py*52 + px*2;
      float v = fmaxf(fmaxf(bf2f(c2[0]), bf2f(c2[1])), fmaxf(bf2f(c2[26]), bf2f(c2[27])));
      outv = f2bf(fmaxf(v + b2[oc], 0.f));
    }
    X[(size_t)m*KPAD + f] = outv;
  }
}

// ---------------------------------------------------------------------------
// Kernel 5: linear GEMM, split-K, 2-phase pipelined.
// out_partial P[s][Mpad][NPAD] f32 = X[64-tile] * Wt[128-tile] over k-chunk.
// BM=64, BN=128, BK=64, 4 waves (2x2), each wave 32x64.
// If splits==1, writes relu(+bias) directly to out.
// ---------------------------------------------------------------------------
__global__ __launch_bounds__(256) void gemm_lin(
    const unsigned short* __restrict__ X, const unsigned short* __restrict__ Wt,
    const float* __restrict__ lin_b, float* __restrict__ P, float* __restrict__ out,
    int M, int Mpad, int splits) {
  __shared__ unsigned short As[2][4096];   //  8KB x2: 64 rows x 64 k
  __shared__ unsigned short Bs[2][8192];   // 16KB x2: 128 rows x 64 k
  int tid = threadIdx.x, lane = tid & 63, wid = tid >> 6;
  int m0 = blockIdx.x * 64, n0 = blockIdx.y * 128;
  int ks = blockIdx.z;
  int itBeg = (ks * 85) / splits, itEnd = ((ks + 1) * 85) / splits;
  int wm = wid >> 1, wn = wid & 1;

  f32x4 acc[2][4];
#pragma unroll
  for (int i = 0; i < 2; i++)
#pragma unroll
    for (int j = 0; j < 4; j++) acc[i][j] = (f32x4){0.f,0.f,0.f,0.f};

  // staging geometry: per issue, 8 rows x 8 slots (1KB), lane -> row=lane>>3, slot=lane&7
  int rsub = lane >> 3;
  int kslot = (lane & 7) ^ rsub;      // inverse-swizzled source slot (row&7 == rsub)
  int kg = lane >> 4;

  auto stage = [&](int buf, int it) {
    size_t kof = (size_t)it * 64 + kslot * 8;
#pragma unroll
    for (int cc = 0; cc < 2; cc++) {
      int chunk = wid + cc*4;                 // 0..7
      int gm = m0 + chunk*8 + rsub;
      gload_lds16(X + (size_t)gm*KPAD + kof, (char*)As[buf] + chunk*1024);
    }
#pragma unroll
    for (int cc = 0; cc < 4; cc++) {
      int chunk = wid + cc*4;                 // 0..15
      int gn = n0 + chunk*8 + rsub;
      gload_lds16(Wt + (size_t)gn*KPAD + kof, (char*)Bs[buf] + chunk*1024);
    }
  };

  stage(0, itBeg);
  __syncthreads();
  int cur = 0;
  for (int it = itBeg; it < itEnd; ++it) {
    if (it + 1 < itEnd) stage(cur ^ 1, it + 1);
#pragma unroll
    for (int ksub = 0; ksub < 2; ++ksub) {
      int slot = ksub*4 + kg;
      short8 af[2], bfr[4];
#pragma unroll
      for (int mf = 0; mf < 2; mf++) {
        int r = wm*32 + mf*16 + (lane & 15);
        af[mf] = *(const short8*)((const char*)As[cur] + r*128 + ((slot ^ (lane&7))<<4));
      }
#pragma unroll
      for (int nf = 0; nf < 4; nf++) {
        int r = wn*64 + nf*16 + (lane & 15);
        bfr[nf] = *(const short8*)((const char*)Bs[cur] + r*128 + ((slot ^ (lane&7))<<4));
      }
#pragma unroll
      for (int mf = 0; mf < 2; mf++)
#pragma unroll
        for (int nf = 0; nf < 4; nf++)
          acc[mf][nf] = __builtin_amdgcn_mfma_f32_16x16x32_bf16(af[mf], bfr[nf], acc[mf][nf], 0, 0, 0);
    }
    __syncthreads();
    cur ^= 1;
  }

  if (splits == 1) {
#pragma unroll
    for (int mf = 0; mf < 2; mf++)
#pragma unroll
      for (int nf = 0; nf < 4; nf++) {
        int n = n0 + wn*64 + nf*16 + (lane & 15);
#pragma unroll
        for (int r = 0; r < 4; r++) {
          int mm = m0 + wm*32 + mf*16 + ((lane>>4)<<2) + r;
          if (mm < M && n < 4800)
            out[(size_t)mm*4800 + n] = fmaxf(acc[mf][nf][r] + lin_b[n], 0.f);
        }
      }
  } else {
    float* Pp = P + (size_t)ks * Mpad * NPAD;
#pragma unroll
    for (int mf = 0; mf < 2; mf++)
#pragma unroll
      for (int nf = 0; nf < 4; nf++) {
        int n = n0 + wn*64 + nf*16 + (lane & 15);
#pragma unroll
        for (int r = 0; r < 4; r++) {
          int mm = m0 + wm*32 + mf*16 + ((lane>>4)<<2) + r;
          Pp[(size_t)mm*NPAD + n] = acc[mf][nf][r];
        }
      }
  }
}

// ---------------------------------------------------------------------------
// Kernel 6: split-K reduce + bias + relu
// ---------------------------------------------------------------------------
__global__ void reduce_out(const float* __restrict__ P, const float* __restrict__ lb,
                           float* __restrict__ out, int M, int Mpad, int splits) {
  int total = M * 1200;  // float4 granules
  for (int idx = blockIdx.x*256 + threadIdx.x; idx < total; idx += gridDim.x*256) {
    int m = idx / 1200, q = idx - m*1200;
    int n = q * 4;
    f32x4 s = *(const f32x4*)(P + (size_t)m*NPAD + n);
    for (int sidx = 1; sidx < splits; sidx++)
      s += *(const f32x4*)(P + (size_t)sidx*Mpad*NPAD + (size_t)m*NPAD + n);
    f32x4 b = *(const f32x4*)(lb + n);
    f32x4 r;
#pragma unroll
    for (int j = 0; j < 4; j++) r[j] = fmaxf(s[j] + b[j], 0.f);
    *(f32x4*)(out + (size_t)m*4800 + n) = r;
  }
}

// ---------------------------------------------------------------------------
extern "C" void kernel_launch(void* const* d_in, const int* in_sizes, int n_in,
                              void* d_out, int out_size, void* d_ws, size_t ws_size,
                              hipStream_t stream) {
  const float* bboxes = (const float*)d_in[0];
  const int*   num_obj = (const int*)d_in[1];
  const float* w1 = (const float*)d_in[2];
  const float* b1 = (const float*)d_in[3];
  const float* w2 = (const float*)d_in[4];
  const float* b2 = (const float*)d_in[5];
  const float* lw = (const float*)d_in[6];
  const float* lb = (const float*)d_in[7];
  float* out = (float*)d_out;
  int M = out_size / 4803;
  int Mpad = (M + 63) & ~63;

  // pick largest split-K that fits in ws
  size_t fixed = 0;
  auto align512 = [](size_t x) { return (x + 511) & ~(size_t)511; };
  fixed += align512((size_t)M*8*4);            // pairTab
  fixed += align512((size_t)86528*4);          // T
  fixed += align512((size_t)51200*2);          // W2A
  fixed += align512((size_t)4800*KPAD*2);      // Wt
  fixed += align512((size_t)Mpad*KPAD*2);      // X
  int splits = 4;
  while (splits > 1 && fixed + align512((size_t)splits*Mpad*NPAD*4) > ws_size) splits >>= 1;

  char* ws = (char*)d_ws;
  size_t off = 0;
  auto alloc = [&](size_t bytes) {
    off = align512(off);
    char* p = ws + off;
    off += bytes;
    return p;
  };
  int* pairTab = (int*)alloc((size_t)M*8*4);
  float* T = (float*)alloc((size_t)86528*4);
  unsigned short* W2A = (unsigned short*)alloc((size_t)51200*2);
  unsigned short* Wt = (unsigned short*)alloc((size_t)4800*KPAD*2);
  unsigned short* X = (unsigned short*)alloc((size_t)Mpad*KPAD*2);
  float* P = (splits > 1) ? (float*)alloc((size_t)splits*Mpad*NPAD*4) : nullptr;

  prep_pairs<<<1, 256, 0, stream>>>(bboxes, num_obj, M, pairTab, out + (size_t)M*4800);
  prep_tables<<<(137728+255)/256, 256, 0, stream>>>(w1, w2, T, W2A);
  prep_wt<<<dim3(85, 75), 256, 0, stream>>>(lw, Wt);
  pair_conv<<<M, 256, 0, stream>>>(pairTab, T, W2A, b1, b2, X);
  gemm_lin<<<dim3(Mpad/64, 38, splits), 256, 0, stream>>>(X, Wt, lb, P, out, M, Mpad, splits);
  if (splits > 1)
    reduce_out<<<1024, 256, 0, stream>>>(P, lb, out, M, Mpad, splits);
}